// Round 14
// baseline (289.944 us; speedup 1.0000x reference)
//
#include <hip/hip_runtime.h>

typedef int v4i  __attribute__((ext_vector_type(4)));
typedef int v16i __attribute__((ext_vector_type(16)));

__device__ __forceinline__ int pack4i(int a, int b, int c, int d) {
  return (a & 255) | ((b & 255) << 8) | ((c & 255) << 16) | ((d & 255) << 24);
}
// SWAR per-byte add (mod-256 per lane-byte)
__device__ __forceinline__ int badd4(int a, int b) {
  return ((a & 0x7f7f7f7f) + (b & 0x7f7f7f7f)) ^ ((a ^ b) & 0x80808080);
}
// Non-temporal 16 B load (streaming read, no cache allocation). R13 validated
// the mechanism on X (pack 62->50 us): reads from the d_in allocation plateau
// at ~2.7 TB/s and nt-loads recover ~20%. Applied to ALL read-once d_in
// streams (X, W, E, H). Builtin requires ext_vector_type pointer.
__device__ __forceinline__ v4i ntload4(const int* p) {
  return __builtin_nontemporal_load((const v4i*)p);
}

#define MFMA_I8(a, b, c) __builtin_amdgcn_mfma_i32_32x32x32_i8(a, b, c, 0, 0, 0)
// Counted waits + raw barrier (R5-R9-verified): __syncthreads would drain
// vmcnt to 0 and kill the pipeline. BARX orders ds ops then syncs.
#define WAITV(N) asm volatile("s_waitcnt vmcnt(" #N ")" ::: "memory")
#define BARX do { asm volatile("s_waitcnt lgkmcnt(0)" ::: "memory"); \
                  __builtin_amdgcn_s_barrier(); } while (0)

// ---------------------------------------------------------------------------
// Pack (W + E) -> int8, transposed Bt[n][k] (row stride K bytes).
// R14: W/E fast-path loads are non-temporal (read-once d_in streams).
// ---------------------------------------------------------------------------
__device__ void pack_tile(const int* __restrict__ W, const int* __restrict__ E,
                          char* __restrict__ Bt, int K, int N,
                          int nx, int ky, char* lin) {
  const int t = threadIdx.x;
  const int n0 = nx * 64, k0 = ky * 256;
  {
    const int c  = t & 15;          // column group: 4 ints = 16 B
    const int kq = t >> 4;          // 0..15
    const int ng = n0 + c * 4;
    #pragma unroll 4
    for (int s = 0; s < 16; ++s) {
      const int k = s * 16 + kq;
      const long grow = (long)(k0 + k) * N;
      int a0, a1, a2, a3;
      if (ng + 3 < N) {
        v4i wv = ntload4(W + grow + ng);
        v4i ev = ntload4(E + grow + ng);
        a0 = wv.x + ev.x; a1 = wv.y + ev.y; a2 = wv.z + ev.z; a3 = wv.w + ev.w;
      } else {
        a0 = (ng + 0 < N) ? W[grow + ng + 0] + E[grow + ng + 0] : 0;
        a1 = (ng + 1 < N) ? W[grow + ng + 1] + E[grow + ng + 1] : 0;
        a2 = (ng + 2 < N) ? W[grow + ng + 2] + E[grow + ng + 2] : 0;
        a3 = (ng + 3 < N) ? W[grow + ng + 3] + E[grow + ng + 3] : 0;
      }
      *(int*)(lin + k * 68 + c * 4) = pack4i(a0, a1, a2, a3);
    }
  }
  __syncthreads();
  {
    const int n = t & 63, kq = t >> 6;
    char* dst = Bt + (long)(n0 + n) * K + k0 + (kq << 6);
    int outv[16];
    #pragma unroll
    for (int g = 0; g < 16; ++g) {
      const int k = (kq << 6) + (g << 2);
      outv[g] = pack4i(lin[(k + 0) * 68 + n], lin[(k + 1) * 68 + n],
                       lin[(k + 2) * 68 + n], lin[(k + 3) * 68 + n]);
    }
    #pragma unroll
    for (int g = 0; g < 4; ++g)
      *(int4*)(dst + (g << 4)) =
          make_int4(outv[g * 4], outv[g * 4 + 1], outv[g * 4 + 2], outv[g * 4 + 3]);
  }
}

// ---------------------------------------------------------------------------
// pack_all: weights/bias (bid 0..264, W/E nt-loaded) + non-temporal X->X8
// copy (bid 265..1800; 1536 blocks x 16384 ints). R13-validated. X8 stores
// stay cached (gemm1 re-reads X8 8x).
// ---------------------------------------------------------------------------
__global__ __launch_bounds__(256) void pack_all_kernel(
    const int* W1, const int* E1, char* Bt1,
    const int* W2, const int* E2, char* Bt2,
    const int* W3, const int* E3, char* Bt3,
    const int* b1, const int* eb1, int* bs1,
    const int* b2, const int* eb2, int* bs2,
    const int* b3, const int* eb3, int* bs3,
    const int* X, char* X8) {
  __shared__ __align__(16) char smem[17408];
  const int bid = blockIdx.x;
  if (bid < 192) {
    pack_tile(W1, E1, Bt1, 3072, 1024, bid % 16, bid / 16, smem);
  } else if (bid < 256) {
    const int l = bid - 192;
    pack_tile(W2, E2, Bt2, 1024, 1024, l % 16, l / 16, smem);
  } else if (bid < 264) {
    const int l = bid - 256;
    pack_tile(W3, E3, Bt3, 1024, 100, l & 1, l >> 1, smem);
  } else if (bid == 264) {
    const int t = threadIdx.x;
    for (int i = t; i < 1024; i += 256) {
      bs1[i] = b1[i] + eb1[i];
      bs2[i] = b2[i] + eb2[i];
    }
    for (int i = t; i < 128; i += 256)
      bs3[i] = (i < 100) ? (b3[i] + eb3[i]) : 0;
  } else {
    // X: 25,165,824 ints = 1536 blocks x 16384 ints (64 KB in, 16 KB out)
    const int t = threadIdx.x;
    const long base = (long)(bid - 265) * 16384;
    #pragma unroll
    for (int it = 0; it < 2; ++it) {
      const long o = base + it * 8192 + t * 4;
      v4i a0 = ntload4(X + o);
      v4i a1 = ntload4(X + o + 1024);
      v4i a2 = ntload4(X + o + 2048);
      v4i a3 = ntload4(X + o + 3072);
      v4i a4 = ntload4(X + o + 4096);
      v4i a5 = ntload4(X + o + 5120);
      v4i a6 = ntload4(X + o + 6144);
      v4i a7 = ntload4(X + o + 7168);
      *(int*)(X8 + o)        = pack4i(a0.x, a0.y, a0.z, a0.w);
      *(int*)(X8 + o + 1024) = pack4i(a1.x, a1.y, a1.z, a1.w);
      *(int*)(X8 + o + 2048) = pack4i(a2.x, a2.y, a2.z, a2.w);
      *(int*)(X8 + o + 3072) = pack4i(a3.x, a3.y, a3.z, a3.w);
      *(int*)(X8 + o + 4096) = pack4i(a4.x, a4.y, a4.z, a4.w);
      *(int*)(X8 + o + 5120) = pack4i(a5.x, a5.y, a5.z, a5.w);
      *(int*)(X8 + o + 6144) = pack4i(a6.x, a6.y, a6.z, a6.w);
      *(int*)(X8 + o + 7168) = pack4i(a7.x, a7.y, a7.z, a7.w);
    }
  }
}

// ---------------------------------------------------------------------------
// gemm1: R9 version (best measured) + R14 nt-loads on the read-once H
// stream in the epilogue. 128x128, BK=64, 3-stage LDS, depth-2 named-reg
// prefetch, WAITV(4), int8 A = X8, stride-136 transpose epilogue +
// SWAR-add trunc8(H int32).
// ---------------------------------------------------------------------------
__global__ __launch_bounds__(256, 2) void gemm1_kernel(
    const char* __restrict__ A, const char* __restrict__ Btg,
    const int* __restrict__ bsum, const int* __restrict__ H,
    char* __restrict__ A8out) {
  constexpr int K = 3072, KIT = 48;
  __shared__ __align__(16) char smem[61440];
  const int t = threadIdx.x;
  const int bid = blockIdx.x;
  const int mt = bid & 63, nt = bid >> 6;
  const long m0 = (long)mt << 7;
  const int n0 = nt << 7;

  const int lane = t & 63, w = t >> 6;
  const int lc = lane & 31, hg = lane >> 5;
  const int wm = w >> 1, wn = w & 1;

  v16i acc[2][2] = {};

  const int r = t >> 2, q = t & 3;
  const char* Ar0 = A + (m0 + r) * (long)K + q * 16;
  const char* Ar1 = Ar0 + (long)64 * K;
  const char* Br0 = Btg + (long)(n0 + r) * K + q * 16;
  const char* Br1 = Br0 + (long)64 * K;
  const int awo = r * 80 + q * 16;
  const int bwo = 10240 + r * 80 + q * 16;

  const int fa = (wm * 64 + lc) * 80;
  const int fb = 10240 + (wn * 64 + lc) * 80;

  int4 xA0, xA1, xB0, xB1, yA0, yA1, yB0, yB1;

  auto ISSUEX = [&](int kt) {
    const int ko = kt * 64;
    xA0 = *(const int4*)(Ar0 + ko);
    xA1 = *(const int4*)(Ar1 + ko);
    xB0 = *(const int4*)(Br0 + ko);
    xB1 = *(const int4*)(Br1 + ko);
  };
  auto ISSUEY = [&](int kt) {
    const int ko = kt * 64;
    yA0 = *(const int4*)(Ar0 + ko);
    yA1 = *(const int4*)(Ar1 + ko);
    yB0 = *(const int4*)(Br0 + ko);
    yB1 = *(const int4*)(Br1 + ko);
  };
  auto WRITEX = [&](int st) {
    char* base = smem + st * 20480;
    *(int4*)(base + awo)           = xA0;
    *(int4*)(base + awo + 64 * 80) = xA1;
    *(int4*)(base + bwo)           = xB0;
    *(int4*)(base + bwo + 64 * 80) = xB1;
  };
  auto WRITEY = [&](int st) {
    char* base = smem + st * 20480;
    *(int4*)(base + awo)           = yA0;
    *(int4*)(base + awo + 64 * 80) = yA1;
    *(int4*)(base + bwo)           = yB0;
    *(int4*)(base + bwo + 64 * 80) = yB1;
  };
  auto MSTEP = [&](int st) {
    const char* base = smem + st * 20480;
    __builtin_amdgcn_s_setprio(1);
    #pragma unroll
    for (int ks = 0; ks < 2; ++ks) {
      const int sel = ks * 32 + hg * 16;
      v4i a0 = *(const v4i*)(base + fa + sel);
      v4i a1 = *(const v4i*)(base + fa + 32 * 80 + sel);
      v4i b0 = *(const v4i*)(base + fb + sel);
      v4i b1 = *(const v4i*)(base + fb + 32 * 80 + sel);
      acc[0][0] = MFMA_I8(a0, b0, acc[0][0]);
      acc[0][1] = MFMA_I8(a0, b1, acc[0][1]);
      acc[1][0] = MFMA_I8(a1, b0, acc[1][0]);
      acc[1][1] = MFMA_I8(a1, b1, acc[1][1]);
    }
    __builtin_amdgcn_s_setprio(0);
  };

  ISSUEX(0);
  ISSUEY(1);
  WAITV(4);
  WRITEX(0);
  BARX;
  for (int kt = 0; kt < KIT - 2; kt += 2) {
    ISSUEX(kt + 2);
    MSTEP(kt % 3);
    WAITV(4);
    WRITEY((kt + 1) % 3);
    BARX;
    ISSUEY(kt + 3);
    MSTEP((kt + 1) % 3);
    WAITV(4);
    WRITEX((kt + 2) % 3);
    BARX;
  }
  MSTEP((KIT - 2) % 3);
  WAITV(0);
  WRITEY((KIT - 1) % 3);
  BARX;
  MSTEP((KIT - 1) % 3);

  // Epilogue (R7/R9-verified): LDS transpose stride 136 + SWAR-add trunc8(H).
  BARX;
  const int bsv0 = bsum[n0 + wn * 64 + lc];
  const int bsv1 = bsum[n0 + wn * 64 + 32 + lc];
  #pragma unroll
  for (int i = 0; i < 2; ++i) {
    #pragma unroll
    for (int j = 0; j < 2; ++j) {
      const int bv = j ? bsv1 : bsv0;
      const int col = wn * 64 + j * 32 + lc;
      #pragma unroll
      for (int rr = 0; rr < 16; ++rr) {
        const int row = wm * 64 + i * 32 + (hg << 2) + (rr & 3) + ((rr >> 2) << 3);
        smem[row * 136 + col] = (char)(acc[i][j][rr] + bv);
      }
    }
  }
  BARX;
  const char* srcp = smem + (t >> 1) * 136 + (t & 1) * 64;
  const long gco = (m0 + (t >> 1)) * 1024 + n0 + (t & 1) * 64;
  const int* hp = H + gco;
  #pragma unroll
  for (int g = 0; g < 4; ++g) {
    int4 s  = *(const int4*)(srcp + g * 16);
    v4i h0 = ntload4(hp + g * 16);
    v4i h1 = ntload4(hp + g * 16 + 4);
    v4i h2 = ntload4(hp + g * 16 + 8);
    v4i h3 = ntload4(hp + g * 16 + 12);
    s = make_int4(badd4(s.x, pack4i(h0.x, h0.y, h0.z, h0.w)),
                  badd4(s.y, pack4i(h1.x, h1.y, h1.z, h1.w)),
                  badd4(s.z, pack4i(h2.x, h2.y, h2.z, h2.w)),
                  badd4(s.w, pack4i(h3.x, h3.y, h3.z, h3.w)));
    *(int4*)(A8out + gco + g * 16) = s;
  }
}

// ---------------------------------------------------------------------------
// gemm2: R9 version verbatim (128x128, 3-stage, WAITV(4); verified).
// ---------------------------------------------------------------------------
__global__ __launch_bounds__(256, 2) void gemm2_kernel(
    const char* __restrict__ A, const char* __restrict__ Btg,
    const int* __restrict__ bsum, int* __restrict__ Iout) {
  constexpr int K = 1024, KIT = 16;
  __shared__ __align__(16) char smem[61440];
  const int t = threadIdx.x;
  const int bid = blockIdx.x;
  const int mt = bid & 63, nt = bid >> 6;
  const long m0 = (long)mt << 7;
  const int n0 = nt << 7;

  const int lane = t & 63, w = t >> 6;
  const int lc = lane & 31, hg = lane >> 5;
  const int wm = w >> 1, wn = w & 1;

  v16i acc[2][2] = {};

  const int r = t >> 2, q = t & 3;
  const char* Ar0 = A + (m0 + r) * (long)K + q * 16;
  const char* Ar1 = Ar0 + (long)64 * K;
  const char* Br0 = Btg + (long)(n0 + r) * K + q * 16;
  const char* Br1 = Br0 + (long)64 * K;
  const int awo = r * 80 + q * 16;
  const int bwo = 10240 + r * 80 + q * 16;

  const int fa = (wm * 64 + lc) * 80;
  const int fb = 10240 + (wn * 64 + lc) * 80;

  int4 xA0, xA1, xB0, xB1, yA0, yA1, yB0, yB1;

  auto ISSUEX = [&](int kt) {
    const int ko = kt * 64;
    xA0 = *(const int4*)(Ar0 + ko);
    xA1 = *(const int4*)(Ar1 + ko);
    xB0 = *(const int4*)(Br0 + ko);
    xB1 = *(const int4*)(Br1 + ko);
  };
  auto ISSUEY = [&](int kt) {
    const int ko = kt * 64;
    yA0 = *(const int4*)(Ar0 + ko);
    yA1 = *(const int4*)(Ar1 + ko);
    yB0 = *(const int4*)(Br0 + ko);
    yB1 = *(const int4*)(Br1 + ko);
  };
  auto WRITEX = [&](int st) {
    char* base = smem + st * 20480;
    *(int4*)(base + awo)           = xA0;
    *(int4*)(base + awo + 64 * 80) = xA1;
    *(int4*)(base + bwo)           = xB0;
    *(int4*)(base + bwo + 64 * 80) = xB1;
  };
  auto WRITEY = [&](int st) {
    char* base = smem + st * 20480;
    *(int4*)(base + awo)           = yA0;
    *(int4*)(base + awo + 64 * 80) = yA1;
    *(int4*)(base + bwo)           = yB0;
    *(int4*)(base + bwo + 64 * 80) = yB1;
  };
  auto MSTEP = [&](int st) {
    const char* base = smem + st * 20480;
    __builtin_amdgcn_s_setprio(1);
    #pragma unroll
    for (int ks = 0; ks < 2; ++ks) {
      const int sel = ks * 32 + hg * 16;
      v4i a0 = *(const v4i*)(base + fa + sel);
      v4i a1 = *(const v4i*)(base + fa + 32 * 80 + sel);
      v4i b0 = *(const v4i*)(base + fb + sel);
      v4i b1 = *(const v4i*)(base + fb + 32 * 80 + sel);
      acc[0][0] = MFMA_I8(a0, b0, acc[0][0]);
      acc[0][1] = MFMA_I8(a0, b1, acc[0][1]);
      acc[1][0] = MFMA_I8(a1, b0, acc[1][0]);
      acc[1][1] = MFMA_I8(a1, b1, acc[1][1]);
    }
    __builtin_amdgcn_s_setprio(0);
  };

  ISSUEX(0);
  ISSUEY(1);
  WAITV(4);
  WRITEX(0);
  BARX;
  for (int kt = 0; kt < KIT - 2; kt += 2) {
    ISSUEX(kt + 2);
    MSTEP(kt % 3);
    WAITV(4);
    WRITEY((kt + 1) % 3);
    BARX;
    ISSUEY(kt + 3);
    MSTEP((kt + 1) % 3);
    WAITV(4);
    WRITEX((kt + 2) % 3);
    BARX;
  }
  MSTEP((KIT - 2) % 3);
  WAITV(0);
  WRITEY((KIT - 1) % 3);
  BARX;
  MSTEP((KIT - 1) % 3);

  const int bsj0 = bsum[n0 + wn * 64 + lc];
  const int bsj1 = bsum[n0 + wn * 64 + 32 + lc];
  #pragma unroll
  for (int i = 0; i < 2; ++i) {
    #pragma unroll
    for (int j = 0; j < 2; ++j) {
      const int bv = j ? bsj1 : bsj0;
      const int col = n0 + wn * 64 + j * 32 + lc;
      #pragma unroll
      for (int rr = 0; rr < 16; ++rr) {
        const long row = m0 + wm * 64 + i * 32 + (hg << 2) + (rr & 3) + ((rr >> 2) << 3);
        Iout[row * 1024 + col] = (int)(signed char)(acc[i][j][rr] + bv);
      }
    }
  }
}

// ---------------------------------------------------------------------------
// Layer 3: 16x128 tile, 512 blocks (2/CU), mfma_i32_16x16x64_i8, 2-stage.
// A = h2 int32 from d_out, packed to int8 in staging. (Long-verified.)
// ---------------------------------------------------------------------------
__global__ __launch_bounds__(256, 2) void gemm3_kernel(
    const int* __restrict__ h2, const char* __restrict__ Btg,
    const int* __restrict__ bsum, int* __restrict__ Iout) {
  // stage: As 16x80 (1280) + Bs 128x80 (10240) = 11520; x2 = 23040
  __shared__ __align__(16) char smem[23040];
  const int t = threadIdx.x;
  const int m0 = blockIdx.x << 4;
  const int lane = t & 63, w = t >> 6;
  const int l16 = lane & 15, q = lane >> 4;
  v4i acc0 = {}, acc1 = {};

  const int am = t >> 4, ah = t & 15;      // 16 rows x 16 thr x 4 ints
  const int* Arow = h2 + (long)(m0 + am) * 1024 + ah * 4;
  const int aoff = am * 80 + ah * 4;
  const int bm = t >> 1, bh = t & 1;       // 128 rows x 2 thr x 32 B
  const char* Brow = Btg + (long)bm * 1024 + bh * 32;
  const int boff = bm * 80 + bh * 32;

  const int abo  = l16 * 80 + q * 16;
  const int bbo0 = (w * 32 + l16) * 80 + q * 16;
  const int bbo1 = (w * 32 + 16 + l16) * 80 + q * 16;

  int4 ar, br0, br1;
  auto LOAD = [&](int kt) {
    const int kb = kt << 6;
    ar  = *(const int4*)(Arow + kb);
    br0 = *(const int4*)(Brow + kb);
    br1 = *(const int4*)(Brow + kb + 16);
  };
  auto STORE = [&](int stage) {
    char* base = smem + stage * 11520;
    *(int*)(base + aoff) = pack4i(ar.x, ar.y, ar.z, ar.w);
    *(int4*)(base + 1280 + boff)      = br0;
    *(int4*)(base + 1280 + boff + 16) = br1;
  };
  auto MFMA = [&](int stage) {
    const char* base = smem + stage * 11520;
    v4i a  = *(const v4i*)(base + abo);
    v4i b0 = *(const v4i*)(base + 1280 + bbo0);
    v4i b1 = *(const v4i*)(base + 1280 + bbo1);
    acc0 = __builtin_amdgcn_mfma_i32_16x16x64_i8(a, b0, acc0, 0, 0, 0);
    acc1 = __builtin_amdgcn_mfma_i32_16x16x64_i8(a, b1, acc1, 0, 0, 0);
  };

  LOAD(0); STORE(0); __syncthreads();
  for (int kt = 0; kt < 16; ++kt) {
    if (kt + 1 < 16) LOAD(kt + 1);
    MFMA(kt & 1);
    if (kt + 1 < 16) { STORE((kt + 1) & 1); __syncthreads(); }
  }

  const int c0 = w * 32 + l16;       // cols {0-15,32-47,64-79,96-111}
  const int c1 = c0 + 16;            // cols {16-31,48-63,80-95,112-127}
  if (c0 < 100) {
    const int b = bsum[c0];
    #pragma unroll
    for (int rr = 0; rr < 4; ++rr)
      Iout[(long)(m0 + q * 4 + rr) * 100 + c0] = (int)(signed char)(acc0[rr] + b);
  }
  if (c1 < 100) {
    const int b = bsum[c1];
    #pragma unroll
    for (int rr = 0; rr < 4; ++rr)
      Iout[(long)(m0 + q * 4 + rr) * 100 + c1] = (int)(signed char)(acc1[rr] + b);
  }
}

// ---------------------------------------------------------------------------
// ws (12.7 MB): Bt1 | Bt2 | Bt3 | bs1 | bs2 | bs3 | A2
// d_out scratch: X8 [0, 25.2 MB) — dead before gemm2 overwrites the region
// with h2 (launch order on one stream guarantees it; R0/R9-proven pattern).
// ---------------------------------------------------------------------------
extern "C" void kernel_launch(void* const* d_in, const int* in_sizes, int n_in,
                              void* d_out, int out_size, void* d_ws, size_t ws_size,
                              hipStream_t stream) {
  (void)in_sizes; (void)n_in; (void)out_size; (void)ws_size;
  const int* W1  = (const int*)d_in[0];
  const int* b1  = (const int*)d_in[1];
  const int* W2  = (const int*)d_in[2];
  const int* b2  = (const int*)d_in[3];
  const int* W3  = (const int*)d_in[4];
  const int* b3  = (const int*)d_in[5];
  const int* E1  = (const int*)d_in[6];
  const int* eb1 = (const int*)d_in[7];
  const int* E2  = (const int*)d_in[8];
  const int* eb2 = (const int*)d_in[9];
  const int* E3  = (const int*)d_in[10];
  const int* eb3 = (const int*)d_in[11];
  const int* X   = (const int*)d_in[12];   // [8192][3072] int32
  const int* H   = (const int*)d_in[13];   // [8192][1024] int32
  int* out = (int*)d_out;                  // h2 [8192*1024] then out [8192*100]

  char* ws  = (char*)d_ws;
  char* Bt1 = ws;                          // 3,145,728
  char* Bt2 = Bt1 + 3145728;               // 1,048,576
  char* Bt3 = Bt2 + 1048576;               //   131,072 (rows 100..127 zeroed)
  int*  bs1 = (int*)(Bt3 + 131072);        // 1024 ints
  int*  bs2 = bs1 + 1024;                  // 1024 ints
  int*  bs3 = bs2 + 1024;                  //  128 ints
  char* A2  = (char*)(bs3 + 128);          // 8,388,608 int8
  char* X8  = (char*)d_out;                // 25,165,824 int8 (temp in d_out)

  pack_all_kernel<<<dim3(1801), dim3(256), 0, stream>>>(
      W1, E1, Bt1, W2, E2, Bt2, W3, E3, Bt3,
      b1, eb1, bs1, b2, eb2, bs2, b3, eb3, bs3, X, X8);

  // Layer 1: X8 (int8) -> i2c ; epilogue adds trunc8(H int32) -> A2
  gemm1_kernel<<<dim3(512), dim3(256), 0, stream>>>(X8, Bt1, bs1, H, A2);

  // Layer 2: h2 -> d_out (int32)
  gemm2_kernel<<<dim3(512), dim3(256), 0, stream>>>(A2, Bt2, bs2, out);

  // Layer 3: reads h2 from d_out (int32), writes out region (int32)
  gemm3_kernel<<<dim3(512), dim3(256), 0, stream>>>(
      out, Bt3, bs3, out + 8388608);
}

// Round 15
// 279.676 us; speedup vs baseline: 1.0367x; 1.0367x over previous
//
#include <hip/hip_runtime.h>

typedef int v4i  __attribute__((ext_vector_type(4)));
typedef int v16i __attribute__((ext_vector_type(16)));

__device__ __forceinline__ int pack4i(int a, int b, int c, int d) {
  return (a & 255) | ((b & 255) << 8) | ((c & 255) << 16) | ((d & 255) << 24);
}
// SWAR per-byte add (mod-256 per lane-byte)
__device__ __forceinline__ int badd4(int a, int b) {
  return ((a & 0x7f7f7f7f) + (b & 0x7f7f7f7f)) ^ ((a ^ b) & 0x80808080);
}
// Non-temporal 16 B load (streaming read, no cache allocation).
// USE ONLY ON COLD STREAMS: R13 validated on X (pack 62->50 us; 100 MB does
// not survive the iteration's working set). R14 falsified on H (gemm1 +6 us:
// H is 33 MB, L3-warm across bench iterations — nt threw the hits away).
__device__ __forceinline__ v4i ntload4(const int* p) {
  return __builtin_nontemporal_load((const v4i*)p);
}

#define MFMA_I8(a, b, c) __builtin_amdgcn_mfma_i32_32x32x32_i8(a, b, c, 0, 0, 0)
// Counted waits + raw barrier (R5-R9-verified): __syncthreads would drain
// vmcnt to 0 and kill the pipeline. BARX orders ds ops then syncs.
#define WAITV(N) asm volatile("s_waitcnt vmcnt(" #N ")" ::: "memory")
#define BARX do { asm volatile("s_waitcnt lgkmcnt(0)" ::: "memory"); \
                  __builtin_amdgcn_s_barrier(); } while (0)

// ---------------------------------------------------------------------------
// Pack (W + E) -> int8, transposed Bt[n][k] (row stride K bytes).
// W/E fast-path loads non-temporal (R14: neutral-or-positive; W/E at 34.6 MB
// combined are partially evicted between iterations).
// ---------------------------------------------------------------------------
__device__ void pack_tile(const int* __restrict__ W, const int* __restrict__ E,
                          char* __restrict__ Bt, int K, int N,
                          int nx, int ky, char* lin) {
  const int t = threadIdx.x;
  const int n0 = nx * 64, k0 = ky * 256;
  {
    const int c  = t & 15;          // column group: 4 ints = 16 B
    const int kq = t >> 4;          // 0..15
    const int ng = n0 + c * 4;
    #pragma unroll 4
    for (int s = 0; s < 16; ++s) {
      const int k = s * 16 + kq;
      const long grow = (long)(k0 + k) * N;
      int a0, a1, a2, a3;
      if (ng + 3 < N) {
        v4i wv = ntload4(W + grow + ng);
        v4i ev = ntload4(E + grow + ng);
        a0 = wv.x + ev.x; a1 = wv.y + ev.y; a2 = wv.z + ev.z; a3 = wv.w + ev.w;
      } else {
        a0 = (ng + 0 < N) ? W[grow + ng + 0] + E[grow + ng + 0] : 0;
        a1 = (ng + 1 < N) ? W[grow + ng + 1] + E[grow + ng + 1] : 0;
        a2 = (ng + 2 < N) ? W[grow + ng + 2] + E[grow + ng + 2] : 0;
        a3 = (ng + 3 < N) ? W[grow + ng + 3] + E[grow + ng + 3] : 0;
      }
      *(int*)(lin + k * 68 + c * 4) = pack4i(a0, a1, a2, a3);
    }
  }
  __syncthreads();
  {
    const int n = t & 63, kq = t >> 6;
    char* dst = Bt + (long)(n0 + n) * K + k0 + (kq << 6);
    int outv[16];
    #pragma unroll
    for (int g = 0; g < 16; ++g) {
      const int k = (kq << 6) + (g << 2);
      outv[g] = pack4i(lin[(k + 0) * 68 + n], lin[(k + 1) * 68 + n],
                       lin[(k + 2) * 68 + n], lin[(k + 3) * 68 + n]);
    }
    #pragma unroll
    for (int g = 0; g < 4; ++g)
      *(int4*)(dst + (g << 4)) =
          make_int4(outv[g * 4], outv[g * 4 + 1], outv[g * 4 + 2], outv[g * 4 + 3]);
  }
}

// ---------------------------------------------------------------------------
// pack_all: weights/bias (bid 0..264, W/E nt-loaded) + non-temporal X->X8
// copy (bid 265..1800; 1536 blocks x 16384 ints). R13-validated. X8 stores
// stay cached (gemm1 re-reads X8 8x).
// ---------------------------------------------------------------------------
__global__ __launch_bounds__(256) void pack_all_kernel(
    const int* W1, const int* E1, char* Bt1,
    const int* W2, const int* E2, char* Bt2,
    const int* W3, const int* E3, char* Bt3,
    const int* b1, const int* eb1, int* bs1,
    const int* b2, const int* eb2, int* bs2,
    const int* b3, const int* eb3, int* bs3,
    const int* X, char* X8) {
  __shared__ __align__(16) char smem[17408];
  const int bid = blockIdx.x;
  if (bid < 192) {
    pack_tile(W1, E1, Bt1, 3072, 1024, bid % 16, bid / 16, smem);
  } else if (bid < 256) {
    const int l = bid - 192;
    pack_tile(W2, E2, Bt2, 1024, 1024, l % 16, l / 16, smem);
  } else if (bid < 264) {
    const int l = bid - 256;
    pack_tile(W3, E3, Bt3, 1024, 100, l & 1, l >> 1, smem);
  } else if (bid == 264) {
    const int t = threadIdx.x;
    for (int i = t; i < 1024; i += 256) {
      bs1[i] = b1[i] + eb1[i];
      bs2[i] = b2[i] + eb2[i];
    }
    for (int i = t; i < 128; i += 256)
      bs3[i] = (i < 100) ? (b3[i] + eb3[i]) : 0;
  } else {
    // X: 25,165,824 ints = 1536 blocks x 16384 ints (64 KB in, 16 KB out)
    const int t = threadIdx.x;
    const long base = (long)(bid - 265) * 16384;
    #pragma unroll
    for (int it = 0; it < 2; ++it) {
      const long o = base + it * 8192 + t * 4;
      v4i a0 = ntload4(X + o);
      v4i a1 = ntload4(X + o + 1024);
      v4i a2 = ntload4(X + o + 2048);
      v4i a3 = ntload4(X + o + 3072);
      v4i a4 = ntload4(X + o + 4096);
      v4i a5 = ntload4(X + o + 5120);
      v4i a6 = ntload4(X + o + 6144);
      v4i a7 = ntload4(X + o + 7168);
      *(int*)(X8 + o)        = pack4i(a0.x, a0.y, a0.z, a0.w);
      *(int*)(X8 + o + 1024) = pack4i(a1.x, a1.y, a1.z, a1.w);
      *(int*)(X8 + o + 2048) = pack4i(a2.x, a2.y, a2.z, a2.w);
      *(int*)(X8 + o + 3072) = pack4i(a3.x, a3.y, a3.z, a3.w);
      *(int*)(X8 + o + 4096) = pack4i(a4.x, a4.y, a4.z, a4.w);
      *(int*)(X8 + o + 5120) = pack4i(a5.x, a5.y, a5.z, a5.w);
      *(int*)(X8 + o + 6144) = pack4i(a6.x, a6.y, a6.z, a6.w);
      *(int*)(X8 + o + 7168) = pack4i(a7.x, a7.y, a7.z, a7.w);
    }
  }
}

// ---------------------------------------------------------------------------
// gemm1: R13 version VERBATIM (best measured). H loads are REGULAR cached
// loads — H is L3-warm across bench iterations (R14's nt-H cost +6 us).
// 128x128, BK=64, 3-stage LDS, depth-2 named-reg prefetch, WAITV(4),
// int8 A = X8, stride-136 transpose epilogue + SWAR-add trunc8(H int32).
// ---------------------------------------------------------------------------
__global__ __launch_bounds__(256, 2) void gemm1_kernel(
    const char* __restrict__ A, const char* __restrict__ Btg,
    const int* __restrict__ bsum, const int* __restrict__ H,
    char* __restrict__ A8out) {
  constexpr int K = 3072, KIT = 48;
  __shared__ __align__(16) char smem[61440];
  const int t = threadIdx.x;
  const int bid = blockIdx.x;
  const int mt = bid & 63, nt = bid >> 6;
  const long m0 = (long)mt << 7;
  const int n0 = nt << 7;

  const int lane = t & 63, w = t >> 6;
  const int lc = lane & 31, hg = lane >> 5;
  const int wm = w >> 1, wn = w & 1;

  v16i acc[2][2] = {};

  const int r = t >> 2, q = t & 3;
  const char* Ar0 = A + (m0 + r) * (long)K + q * 16;
  const char* Ar1 = Ar0 + (long)64 * K;
  const char* Br0 = Btg + (long)(n0 + r) * K + q * 16;
  const char* Br1 = Br0 + (long)64 * K;
  const int awo = r * 80 + q * 16;
  const int bwo = 10240 + r * 80 + q * 16;

  const int fa = (wm * 64 + lc) * 80;
  const int fb = 10240 + (wn * 64 + lc) * 80;

  int4 xA0, xA1, xB0, xB1, yA0, yA1, yB0, yB1;

  auto ISSUEX = [&](int kt) {
    const int ko = kt * 64;
    xA0 = *(const int4*)(Ar0 + ko);
    xA1 = *(const int4*)(Ar1 + ko);
    xB0 = *(const int4*)(Br0 + ko);
    xB1 = *(const int4*)(Br1 + ko);
  };
  auto ISSUEY = [&](int kt) {
    const int ko = kt * 64;
    yA0 = *(const int4*)(Ar0 + ko);
    yA1 = *(const int4*)(Ar1 + ko);
    yB0 = *(const int4*)(Br0 + ko);
    yB1 = *(const int4*)(Br1 + ko);
  };
  auto WRITEX = [&](int st) {
    char* base = smem + st * 20480;
    *(int4*)(base + awo)           = xA0;
    *(int4*)(base + awo + 64 * 80) = xA1;
    *(int4*)(base + bwo)           = xB0;
    *(int4*)(base + bwo + 64 * 80) = xB1;
  };
  auto WRITEY = [&](int st) {
    char* base = smem + st * 20480;
    *(int4*)(base + awo)           = yA0;
    *(int4*)(base + awo + 64 * 80) = yA1;
    *(int4*)(base + bwo)           = yB0;
    *(int4*)(base + bwo + 64 * 80) = yB1;
  };
  auto MSTEP = [&](int st) {
    const char* base = smem + st * 20480;
    __builtin_amdgcn_s_setprio(1);
    #pragma unroll
    for (int ks = 0; ks < 2; ++ks) {
      const int sel = ks * 32 + hg * 16;
      v4i a0 = *(const v4i*)(base + fa + sel);
      v4i a1 = *(const v4i*)(base + fa + 32 * 80 + sel);
      v4i b0 = *(const v4i*)(base + fb + sel);
      v4i b1 = *(const v4i*)(base + fb + 32 * 80 + sel);
      acc[0][0] = MFMA_I8(a0, b0, acc[0][0]);
      acc[0][1] = MFMA_I8(a0, b1, acc[0][1]);
      acc[1][0] = MFMA_I8(a1, b0, acc[1][0]);
      acc[1][1] = MFMA_I8(a1, b1, acc[1][1]);
    }
    __builtin_amdgcn_s_setprio(0);
  };

  ISSUEX(0);
  ISSUEY(1);
  WAITV(4);
  WRITEX(0);
  BARX;
  for (int kt = 0; kt < KIT - 2; kt += 2) {
    ISSUEX(kt + 2);
    MSTEP(kt % 3);
    WAITV(4);
    WRITEY((kt + 1) % 3);
    BARX;
    ISSUEY(kt + 3);
    MSTEP((kt + 1) % 3);
    WAITV(4);
    WRITEX((kt + 2) % 3);
    BARX;
  }
  MSTEP((KIT - 2) % 3);
  WAITV(0);
  WRITEY((KIT - 1) % 3);
  BARX;
  MSTEP((KIT - 1) % 3);

  // Epilogue (R7/R9-verified): LDS transpose stride 136 + SWAR-add trunc8(H).
  BARX;
  const int bsv0 = bsum[n0 + wn * 64 + lc];
  const int bsv1 = bsum[n0 + wn * 64 + 32 + lc];
  #pragma unroll
  for (int i = 0; i < 2; ++i) {
    #pragma unroll
    for (int j = 0; j < 2; ++j) {
      const int bv = j ? bsv1 : bsv0;
      const int col = wn * 64 + j * 32 + lc;
      #pragma unroll
      for (int rr = 0; rr < 16; ++rr) {
        const int row = wm * 64 + i * 32 + (hg << 2) + (rr & 3) + ((rr >> 2) << 3);
        smem[row * 136 + col] = (char)(acc[i][j][rr] + bv);
      }
    }
  }
  BARX;
  const char* srcp = smem + (t >> 1) * 136 + (t & 1) * 64;
  const long gco = (m0 + (t >> 1)) * 1024 + n0 + (t & 1) * 64;
  const int* hp = H + gco;
  #pragma unroll
  for (int g = 0; g < 4; ++g) {
    int4 s  = *(const int4*)(srcp + g * 16);
    int4 h0 = *(const int4*)(hp + g * 16);
    int4 h1 = *(const int4*)(hp + g * 16 + 4);
    int4 h2 = *(const int4*)(hp + g * 16 + 8);
    int4 h3 = *(const int4*)(hp + g * 16 + 12);
    s = make_int4(badd4(s.x, pack4i(h0.x, h0.y, h0.z, h0.w)),
                  badd4(s.y, pack4i(h1.x, h1.y, h1.z, h1.w)),
                  badd4(s.z, pack4i(h2.x, h2.y, h2.z, h2.w)),
                  badd4(s.w, pack4i(h3.x, h3.y, h3.z, h3.w)));
    *(int4*)(A8out + gco + g * 16) = s;
  }
}

// ---------------------------------------------------------------------------
// gemm2: R9 version verbatim (128x128, 3-stage, WAITV(4); verified).
// ---------------------------------------------------------------------------
__global__ __launch_bounds__(256, 2) void gemm2_kernel(
    const char* __restrict__ A, const char* __restrict__ Btg,
    const int* __restrict__ bsum, int* __restrict__ Iout) {
  constexpr int K = 1024, KIT = 16;
  __shared__ __align__(16) char smem[61440];
  const int t = threadIdx.x;
  const int bid = blockIdx.x;
  const int mt = bid & 63, nt = bid >> 6;
  const long m0 = (long)mt << 7;
  const int n0 = nt << 7;

  const int lane = t & 63, w = t >> 6;
  const int lc = lane & 31, hg = lane >> 5;
  const int wm = w >> 1, wn = w & 1;

  v16i acc[2][2] = {};

  const int r = t >> 2, q = t & 3;
  const char* Ar0 = A + (m0 + r) * (long)K + q * 16;
  const char* Ar1 = Ar0 + (long)64 * K;
  const char* Br0 = Btg + (long)(n0 + r) * K + q * 16;
  const char* Br1 = Br0 + (long)64 * K;
  const int awo = r * 80 + q * 16;
  const int bwo = 10240 + r * 80 + q * 16;

  const int fa = (wm * 64 + lc) * 80;
  const int fb = 10240 + (wn * 64 + lc) * 80;

  int4 xA0, xA1, xB0, xB1, yA0, yA1, yB0, yB1;

  auto ISSUEX = [&](int kt) {
    const int ko = kt * 64;
    xA0 = *(const int4*)(Ar0 + ko);
    xA1 = *(const int4*)(Ar1 + ko);
    xB0 = *(const int4*)(Br0 + ko);
    xB1 = *(const int4*)(Br1 + ko);
  };
  auto ISSUEY = [&](int kt) {
    const int ko = kt * 64;
    yA0 = *(const int4*)(Ar0 + ko);
    yA1 = *(const int4*)(Ar1 + ko);
    yB0 = *(const int4*)(Br0 + ko);
    yB1 = *(const int4*)(Br1 + ko);
  };
  auto WRITEX = [&](int st) {
    char* base = smem + st * 20480;
    *(int4*)(base + awo)           = xA0;
    *(int4*)(base + awo + 64 * 80) = xA1;
    *(int4*)(base + bwo)           = xB0;
    *(int4*)(base + bwo + 64 * 80) = xB1;
  };
  auto WRITEY = [&](int st) {
    char* base = smem + st * 20480;
    *(int4*)(base + awo)           = yA0;
    *(int4*)(base + awo + 64 * 80) = yA1;
    *(int4*)(base + bwo)           = yB0;
    *(int4*)(base + bwo + 64 * 80) = yB1;
  };
  auto MSTEP = [&](int st) {
    const char* base = smem + st * 20480;
    __builtin_amdgcn_s_setprio(1);
    #pragma unroll
    for (int ks = 0; ks < 2; ++ks) {
      const int sel = ks * 32 + hg * 16;
      v4i a0 = *(const v4i*)(base + fa + sel);
      v4i a1 = *(const v4i*)(base + fa + 32 * 80 + sel);
      v4i b0 = *(const v4i*)(base + fb + sel);
      v4i b1 = *(const v4i*)(base + fb + 32 * 80 + sel);
      acc[0][0] = MFMA_I8(a0, b0, acc[0][0]);
      acc[0][1] = MFMA_I8(a0, b1, acc[0][1]);
      acc[1][0] = MFMA_I8(a1, b0, acc[1][0]);
      acc[1][1] = MFMA_I8(a1, b1, acc[1][1]);
    }
    __builtin_amdgcn_s_setprio(0);
  };

  ISSUEX(0);
  ISSUEY(1);
  WAITV(4);
  WRITEX(0);
  BARX;
  for (int kt = 0; kt < KIT - 2; kt += 2) {
    ISSUEX(kt + 2);
    MSTEP(kt % 3);
    WAITV(4);
    WRITEY((kt + 1) % 3);
    BARX;
    ISSUEY(kt + 3);
    MSTEP((kt + 1) % 3);
    WAITV(4);
    WRITEX((kt + 2) % 3);
    BARX;
  }
  MSTEP((KIT - 2) % 3);
  WAITV(0);
  WRITEY((KIT - 1) % 3);
  BARX;
  MSTEP((KIT - 1) % 3);

  const int bsj0 = bsum[n0 + wn * 64 + lc];
  const int bsj1 = bsum[n0 + wn * 64 + 32 + lc];
  #pragma unroll
  for (int i = 0; i < 2; ++i) {
    #pragma unroll
    for (int j = 0; j < 2; ++j) {
      const int bv = j ? bsj1 : bsj0;
      const int col = n0 + wn * 64 + j * 32 + lc;
      #pragma unroll
      for (int rr = 0; rr < 16; ++rr) {
        const long row = m0 + wm * 64 + i * 32 + (hg << 2) + (rr & 3) + ((rr >> 2) << 3);
        Iout[row * 1024 + col] = (int)(signed char)(acc[i][j][rr] + bv);
      }
    }
  }
}

// ---------------------------------------------------------------------------
// Layer 3: 16x128 tile, 512 blocks (2/CU), mfma_i32_16x16x64_i8, 2-stage.
// A = h2 int32 from d_out, packed to int8 in staging. (Long-verified.)
// ---------------------------------------------------------------------------
__global__ __launch_bounds__(256, 2) void gemm3_kernel(
    const int* __restrict__ h2, const char* __restrict__ Btg,
    const int* __restrict__ bsum, int* __restrict__ Iout) {
  // stage: As 16x80 (1280) + Bs 128x80 (10240) = 11520; x2 = 23040
  __shared__ __align__(16) char smem[23040];
  const int t = threadIdx.x;
  const int m0 = blockIdx.x << 4;
  const int lane = t & 63, w = t >> 6;
  const int l16 = lane & 15, q = lane >> 4;
  v4i acc0 = {}, acc1 = {};

  const int am = t >> 4, ah = t & 15;      // 16 rows x 16 thr x 4 ints
  const int* Arow = h2 + (long)(m0 + am) * 1024 + ah * 4;
  const int aoff = am * 80 + ah * 4;
  const int bm = t >> 1, bh = t & 1;       // 128 rows x 2 thr x 32 B
  const char* Brow = Btg + (long)bm * 1024 + bh * 32;
  const int boff = bm * 80 + bh * 32;

  const int abo  = l16 * 80 + q * 16;
  const int bbo0 = (w * 32 + l16) * 80 + q * 16;
  const int bbo1 = (w * 32 + 16 + l16) * 80 + q * 16;

  int4 ar, br0, br1;
  auto LOAD = [&](int kt) {
    const int kb = kt << 6;
    ar  = *(const int4*)(Arow + kb);
    br0 = *(const int4*)(Brow + kb);
    br1 = *(const int4*)(Brow + kb + 16);
  };
  auto STORE = [&](int stage) {
    char* base = smem + stage * 11520;
    *(int*)(base + aoff) = pack4i(ar.x, ar.y, ar.z, ar.w);
    *(int4*)(base + 1280 + boff)      = br0;
    *(int4*)(base + 1280 + boff + 16) = br1;
  };
  auto MFMA = [&](int stage) {
    const char* base = smem + stage * 11520;
    v4i a  = *(const v4i*)(base + abo);
    v4i b0 = *(const v4i*)(base + 1280 + bbo0);
    v4i b1 = *(const v4i*)(base + 1280 + bbo1);
    acc0 = __builtin_amdgcn_mfma_i32_16x16x64_i8(a, b0, acc0, 0, 0, 0);
    acc1 = __builtin_amdgcn_mfma_i32_16x16x64_i8(a, b1, acc1, 0, 0, 0);
  };

  LOAD(0); STORE(0); __syncthreads();
  for (int kt = 0; kt < 16; ++kt) {
    if (kt + 1 < 16) LOAD(kt + 1);
    MFMA(kt & 1);
    if (kt + 1 < 16) { STORE((kt + 1) & 1); __syncthreads(); }
  }

  const int c0 = w * 32 + l16;       // cols {0-15,32-47,64-79,96-111}
  const int c1 = c0 + 16;            // cols {16-31,48-63,80-95,112-127}
  if (c0 < 100) {
    const int b = bsum[c0];
    #pragma unroll
    for (int rr = 0; rr < 4; ++rr)
      Iout[(long)(m0 + q * 4 + rr) * 100 + c0] = (int)(signed char)(acc0[rr] + b);
  }
  if (c1 < 100) {
    const int b = bsum[c1];
    #pragma unroll
    for (int rr = 0; rr < 4; ++rr)
      Iout[(long)(m0 + q * 4 + rr) * 100 + c1] = (int)(signed char)(acc1[rr] + b);
  }
}

// ---------------------------------------------------------------------------
// ws (12.7 MB): Bt1 | Bt2 | Bt3 | bs1 | bs2 | bs3 | A2
// d_out scratch: X8 [0, 25.2 MB) — dead before gemm2 overwrites the region
// with h2 (launch order on one stream guarantees it; R0/R9-proven pattern).
// ---------------------------------------------------------------------------
extern "C" void kernel_launch(void* const* d_in, const int* in_sizes, int n_in,
                              void* d_out, int out_size, void* d_ws, size_t ws_size,
                              hipStream_t stream) {
  (void)in_sizes; (void)n_in; (void)out_size; (void)ws_size;
  const int* W1  = (const int*)d_in[0];
  const int* b1  = (const int*)d_in[1];
  const int* W2  = (const int*)d_in[2];
  const int* b2  = (const int*)d_in[3];
  const int* W3  = (const int*)d_in[4];
  const int* b3  = (const int*)d_in[5];
  const int* E1  = (const int*)d_in[6];
  const int* eb1 = (const int*)d_in[7];
  const int* E2  = (const int*)d_in[8];
  const int* eb2 = (const int*)d_in[9];
  const int* E3  = (const int*)d_in[10];
  const int* eb3 = (const int*)d_in[11];
  const int* X   = (const int*)d_in[12];   // [8192][3072] int32
  const int* H   = (const int*)d_in[13];   // [8192][1024] int32
  int* out = (int*)d_out;                  // h2 [8192*1024] then out [8192*100]

  char* ws  = (char*)d_ws;
  char* Bt1 = ws;                          // 3,145,728
  char* Bt2 = Bt1 + 3145728;               // 1,048,576
  char* Bt3 = Bt2 + 1048576;               //   131,072 (rows 100..127 zeroed)
  int*  bs1 = (int*)(Bt3 + 131072);        // 1024 ints
  int*  bs2 = bs1 + 1024;                  // 1024 ints
  int*  bs3 = bs2 + 1024;                  //  128 ints
  char* A2  = (char*)(bs3 + 128);          // 8,388,608 int8
  char* X8  = (char*)d_out;                // 25,165,824 int8 (temp in d_out)

  pack_all_kernel<<<dim3(1801), dim3(256), 0, stream>>>(
      W1, E1, Bt1, W2, E2, Bt2, W3, E3, Bt3,
      b1, eb1, bs1, b2, eb2, bs2, b3, eb3, bs3, X, X8);

  // Layer 1: X8 (int8) -> i2c ; epilogue adds trunc8(H int32) -> A2
  gemm1_kernel<<<dim3(512), dim3(256), 0, stream>>>(X8, Bt1, bs1, H, A2);

  // Layer 2: h2 -> d_out (int32)
  gemm2_kernel<<<dim3(512), dim3(256), 0, stream>>>(A2, Bt2, bs2, out);

  // Layer 3: reads h2 from d_out (int32), writes out region (int32)
  gemm3_kernel<<<dim3(512), dim3(256), 0, stream>>>(
      out, Bt3, bs3, out + 8388608);
}